// Round 2
// baseline (518.150 us; speedup 1.0000x reference)
//
#include <hip/hip_runtime.h>
#include <hip/hip_bf16.h>

// ---------------- problem constants ----------------
constexpr int T  = 16384;   // B*S tokens
constexpr int Dh = 768;
constexpr int Fh = 3072;
constexpr int Eh = 8;
constexpr int MAXT2 = T / 256 + Eh;   // 72 tiles max at 256-row granularity

typedef unsigned short ushort_t;
typedef __attribute__((ext_vector_type(8))) short  bf16x8;  // 8 bf16 = 4 VGPRs
typedef __attribute__((ext_vector_type(4))) float  f32x4;

// fp32 -> bf16 round-to-nearest-even (finite inputs)
static __device__ __forceinline__ ushort_t f2bf(float f) {
    unsigned u = __builtin_bit_cast(unsigned, f);
    u += 0x7FFFu + ((u >> 16) & 1u);
    return (ushort_t)(u >> 16);
}

// ---------------- router v2: 16 tokens per 1024-thread block ----------------
__global__ __launch_bounds__(1024) void router_kernel(
    const float* __restrict__ x, const float* __restrict__ rw,
    float* __restrict__ logits_out, float* __restrict__ eidx_out,
    float* __restrict__ topp, int* __restrict__ counts, int* __restrict__ perm) {

    __shared__ float rwT[Eh][Dh];   // 24 KB, transposed router weights
    __shared__ int   sAmax[16];
    __shared__ int   sBase[Eh];

    int tid = threadIdx.x;
    for (int i = tid; i < Dh * Eh; i += 1024) {
        int d = i >> 3, e = i & 7;
        rwT[e][d] = rw[i];
    }
    __syncthreads();

    int wave = tid >> 6, lane = tid & 63;
    int t = blockIdx.x * 16 + wave;
    const float* xr = x + (size_t)t * Dh;

    double acc[Eh];
#pragma unroll
    for (int e = 0; e < Eh; ++e) acc[e] = 0.0;

#pragma unroll
    for (int j = 0; j < Dh / 256; ++j) {
        int d = lane * 4 + j * 256;
        const float4 xv = *(const float4*)(xr + d);
#pragma unroll
        for (int e = 0; e < Eh; ++e) {
            const float4 w = *(const float4*)&rwT[e][d];
            acc[e] += (double)xv.x * (double)w.x + (double)xv.y * (double)w.y
                    + (double)xv.z * (double)w.z + (double)xv.w * (double)w.w;
        }
    }
#pragma unroll
    for (int off = 32; off > 0; off >>= 1) {
#pragma unroll
        for (int e = 0; e < Eh; ++e) acc[e] += __shfl_xor(acc[e], off, 64);
    }

    int amax = 0;
    if (lane == 0) {
        float l32[Eh];
        float m = -3.4e38f;
#pragma unroll
        for (int e = 0; e < Eh; ++e) l32[e] = (float)acc[e];
#pragma unroll
        for (int e = 0; e < Eh; ++e) {
            if (l32[e] > m) { m = l32[e]; amax = e; }  // strict > : first max wins
        }
        float s = 0.f;
#pragma unroll
        for (int e = 0; e < Eh; ++e) s += expf(l32[e] - m);
#pragma unroll
        for (int e = 0; e < Eh; ++e) logits_out[(size_t)t * Eh + e] = l32[e];
        eidx_out[t] = (float)amax;
        topp[t]     = 1.0f / s;
        sAmax[wave] = amax;
    }
    __syncthreads();

    if (tid < Eh) {
        int c = 0;
#pragma unroll
        for (int w = 0; w < 16; ++w) c += (sAmax[w] == tid);
        sBase[tid] = (c > 0) ? atomicAdd(&counts[tid], c) : 0;
    }
    __syncthreads();

    if (lane == 0) {
        int prior = 0;
        for (int w = 0; w < wave; ++w) prior += (sAmax[w] == amax);
        perm[amax * T + sBase[amax] + prior] = t;
    }
}

// ---------------- scan counts + build tile list: parallel over 8 lanes ----------------
__global__ void scan_counts(const int* counts, int* offsets,
                            int* tE, int* tGoff, int* tSlot0, int* tRows, int* nT) {
    int lane = threadIdx.x;
    if (lane < Eh) {
        int coff = 0, toff = 0;
        for (int e = 0; e < lane; ++e) {
            int ce = counts[e];
            coff += ce;
            toff += (ce + 255) >> 8;
        }
        int c = counts[lane];
        offsets[lane] = coff;
        int myt = (c + 255) >> 8;
        for (int k = 0; k < myt; ++k) {
            int idx = toff + k;
            tE[idx]     = lane;
            tGoff[idx]  = coff + k * 256;
            tSlot0[idx] = k * 256;
            int rem = c - k * 256;
            tRows[idx]  = rem < 256 ? rem : 256;
        }
        if (lane == Eh - 1) {
            offsets[Eh] = coff + c;
            nT[0] = toff + myt;
        }
    }
}

// ---------------- gather tokens into expert-sorted bf16 rows ----------------
__global__ void gather_cast_x(const float* __restrict__ x, const int* __restrict__ offsets,
                              const int* __restrict__ perm, ushort_t* __restrict__ Xg) {
    __shared__ int soff[Eh + 1];
    if (threadIdx.x < Eh + 1) soff[threadIdx.x] = offsets[threadIdx.x];
    __syncthreads();
    int q  = blockIdx.x * 256 + threadIdx.x;     // float4 index, exact grid
    int g  = q / (Dh / 4);
    int cq = (q - g * (Dh / 4)) * 4;
    int e = 0;
#pragma unroll
    for (int i = 1; i < Eh; ++i) e += (g >= soff[i]);
    int tok = perm[e * T + (g - soff[e])];
    const float4 v = *(const float4*)(x + (size_t)tok * Dh + cq);
    ushort4 o;
    o.x = f2bf(v.x); o.y = f2bf(v.y); o.z = f2bf(v.z); o.w = f2bf(v.w);
    *(ushort4*)(Xg + (size_t)g * Dh + cq) = o;
}

// ---------------- transpose + cast weights: src[R][C] fp32 -> dst[C][R] bf16 ----------------
__global__ void transpose_cvt(const float* __restrict__ src, ushort_t* __restrict__ dst,
                              int R, int C) {
    __shared__ ushort_t tile[32][33];
    int tx = threadIdx.x, ty = threadIdx.y;      // block (32, 8)
    size_t base = (size_t)blockIdx.z * (size_t)R * (size_t)C;
    int c0 = blockIdx.x * 32, r0 = blockIdx.y * 32;
#pragma unroll
    for (int j = 0; j < 4; ++j) {
        int r = ty + j * 8;
        tile[r][tx] = f2bf(src[base + (size_t)(r0 + r) * C + c0 + tx]);
    }
    __syncthreads();
    int idx = ty * 32 + tx;
#pragma unroll
    for (int j = 0; j < 2; ++j) {
        int lin = idx + j * 256;
        int c  = lin >> 4;
        int rp = (lin & 15) * 2;
        ushort2 o = { tile[rp][c], tile[rp + 1][c] };
        *(ushort2*)(dst + base + (size_t)(c0 + c) * R + r0 + rp) = o;
    }
}

// ---------------- grouped GEMM v4: 256x256 tile, 8 waves, fixed per-wave 128x64 sub-tile ----
// A: [slot][KTOT] bf16 (expert-sorted rows). B: [E][NTOT][KTOT] bf16.
// LDS XOR-swizzle: row r's 16-B chunk g holds source chunk g ^ (r&7)
// (pre-swizzled global source, linear global_load_lds dest, swizzled ds_read).
// Wave (wr,wc) in 2x4 grid owns rows [wr*128,+128) x cols [wc*64,+64): acc[8][4].
// Per K-tile (BK=64), 4 phases: p0 reads all 8 B-frags (held in regs for the K-tile)
// + A-frags mi={0,1}; p1..p3 read A-frags mi={2p,2p+1}. 24 ds_read_b128 + 64 MFMA
// per wave per K-tile (each fragment read exactly once).
// Staging (counted vmcnt, never 0 mid-loop):
//   p0: A(t+1) -> buf^1  (buf^1 A freed by the barrier ending iter t-1)
//   p1: B(t+2) -> buf    (buf B fully consumed by p0's MFMA + barrier)
//   p3: vmcnt(4) guarantees tile t+1 landed (leaves B(t+2) in flight)
// MODE 0: h = relu(A*B^T) -> bf16, rows = global slot. MODE 1: out = prob*(A*B^T) -> fp32.
template<int KTOT, int NTOT, int MODE>
__global__ __launch_bounds__(512, 2) void moe_gemm2(
    const ushort_t* __restrict__ Aall, const ushort_t* __restrict__ Ball,
    const int* __restrict__ tE, const int* __restrict__ tGoff,
    const int* __restrict__ tSlot0, const int* __restrict__ tRows,
    const int* __restrict__ nT,
    const int* __restrict__ perm, const float* __restrict__ topp,
    void* __restrict__ Cout)
{
    int i = blockIdx.x;
    if (i >= nT[0]) return;
    int e     = tE[i];
    int goff  = tGoff[i];
    int slot0 = tSlot0[i];
    int rows  = tRows[i];
    int n0    = blockIdx.y * 256;

    const ushort_t* Ap = Aall + (size_t)goff * KTOT;
    const ushort_t* Bp = Ball + (size_t)e * KTOT * NTOT + (size_t)n0 * KTOT;

    __shared__ ushort_t As[2][256 * 64];   // 64 KB
    __shared__ ushort_t Bs[2][256 * 64];   // 64 KB
    __shared__ int   tokLds[256];
    __shared__ float probLds[256];

    int tid = threadIdx.x, lane = tid & 63, wid = tid >> 6;
    int wr = wid >> 2, wc = wid & 3;       // wave owns rows wr*128..+128, cols wc*64..+64
    int gq = lane >> 4, lm = lane & 15, l7 = lane & 7;

    if (MODE == 1 && tid < 256) {
        int tok = (tid < rows) ? perm[e * T + slot0 + tid] : 0;
        tokLds[tid]  = tok;
        probLds[tid] = (tid < rows) ? topp[tok] : 0.f;
    }

    f32x4 acc[8][4];                       // [mi 16-row frag][ni 16-col frag]
    const f32x4 zero = {0.f, 0.f, 0.f, 0.f};
#pragma unroll
    for (int mi = 0; mi < 8; ++mi)
#pragma unroll
        for (int ni = 0; ni < 4; ++ni) acc[mi][ni] = zero;

    bf16x8 af[2][2];                       // transient per phase
    bf16x8 bb[2][4];                       // held across the K-tile

    // ---- staging: one full 256x64 tile = 4 x 16B loads/thread ----
#define STAGE_A(BUF, KT) { \
    _Pragma("unroll") \
    for (int j = 0; j < 4; ++j) { \
        int c_ = tid + j * 512; \
        int rr = c_ >> 3, gg = c_ & 7; \
        int srow_ = rr < rows ? rr : rows - 1; \
        const ushort_t* src_ = Ap + (size_t)srow_ * KTOT + (size_t)(KT) * 64 + ((gg ^ (rr & 7)) << 3); \
        __builtin_amdgcn_global_load_lds( \
            (const __attribute__((address_space(1))) unsigned int*)src_, \
            (__attribute__((address_space(3))) unsigned int*)&As[BUF][rr * 64 + gg * 8], 16, 0, 0); \
    } }

#define STAGE_B(BUF, KT) { \
    _Pragma("unroll") \
    for (int j = 0; j < 4; ++j) { \
        int c_ = tid + j * 512; \
        int rr = c_ >> 3, gg = c_ & 7; \
        const ushort_t* src_ = Bp + (size_t)rr * KTOT + (size_t)(KT) * 64 + ((gg ^ (rr & 7)) << 3); \
        __builtin_amdgcn_global_load_lds( \
            (const __attribute__((address_space(1))) unsigned int*)src_, \
            (__attribute__((address_space(3))) unsigned int*)&Bs[BUF][rr * 64 + gg * 8], 16, 0, 0); \
    } }

#define READ_A(TB, P) { \
    _Pragma("unroll") \
    for (int ks = 0; ks < 2; ++ks) \
        _Pragma("unroll") \
        for (int j = 0; j < 2; ++j) \
            af[ks][j] = *(const bf16x8*)&As[TB][ \
                (wr * 128 + ((P) * 2 + j) * 16 + lm) * 64 + ((((ks << 2) + gq) ^ l7) << 3)]; \
    }

#define READ_B(TB) { \
    _Pragma("unroll") \
    for (int ks = 0; ks < 2; ++ks) \
        _Pragma("unroll") \
        for (int ni = 0; ni < 4; ++ni) \
            bb[ks][ni] = *(const bf16x8*)&Bs[TB][ \
                (wc * 64 + ni * 16 + lm) * 64 + ((((ks << 2) + gq) ^ l7) << 3)]; \
    }

#define MFMA_P(P) { \
    __builtin_amdgcn_s_setprio(1); \
    _Pragma("unroll") \
    for (int ks = 0; ks < 2; ++ks) \
        _Pragma("unroll") \
        for (int j = 0; j < 2; ++j) \
            _Pragma("unroll") \
            for (int ni = 0; ni < 4; ++ni) \
                acc[(P) * 2 + j][ni] = __builtin_amdgcn_mfma_f32_16x16x32_bf16( \
                    af[ks][j], bb[ks][ni], acc[(P) * 2 + j][ni], 0, 0, 0); \
    __builtin_amdgcn_s_setprio(0); }

    const int nkt = KTOT / 64;

    // ---- prologue: tile 0 fully + B(1); vmcnt(4) guarantees tile 0 ----
    STAGE_A(0, 0);
    STAGE_B(0, 0);
    if (nkt > 1) {
        STAGE_B(1, 1);
        asm volatile("s_waitcnt vmcnt(4)" ::: "memory");
    } else {
        asm volatile("s_waitcnt vmcnt(0)" ::: "memory");
    }
    __builtin_amdgcn_sched_barrier(0);
    __builtin_amdgcn_s_barrier();

    for (int t = 0; t < nkt; ++t) {
        const int TB = t & 1;

        // ---- phase 0: all B-frags + A mi{0,1}; stage A(t+1) -> buf^1
        READ_B(TB);
        READ_A(TB, 0);
        if (t + 1 < nkt) STAGE_A(TB ^ 1, t + 1);
        __builtin_amdgcn_s_barrier();
        MFMA_P(0);
        __builtin_amdgcn_s_barrier();

        // ---- phase 1: A mi{2,3}; stage B(t+2) -> buf (B(t) consumed at p0)
        READ_A(TB, 1);
        if (t + 2 < nkt) STAGE_B(TB, t + 2);
        __builtin_amdgcn_s_barrier();
        MFMA_P(1);
        __builtin_amdgcn_s_barrier();

        // ---- phase 2: A mi{4,5}
        READ_A(TB, 2);
        __builtin_amdgcn_s_barrier();
        MFMA_P(2);
        __builtin_amdgcn_s_barrier();

        // ---- phase 3: A mi{6,7}; counted vmcnt guarantees tile t+1 landed
        READ_A(TB, 3);
        if (t + 2 < nkt) {
            asm volatile("s_waitcnt vmcnt(4)" ::: "memory");
            __builtin_amdgcn_sched_barrier(0);
        } else if (t + 1 < nkt) {
            asm volatile("s_waitcnt vmcnt(0)" ::: "memory");
            __builtin_amdgcn_sched_barrier(0);
        }
        __builtin_amdgcn_s_barrier();
        MFMA_P(3);
        __builtin_amdgcn_s_barrier();
    }

    // ---- epilogue: C layout col = lane&15, row = (lane>>4)*4 + reg ----
    int cr = (lane >> 4) * 4;
    int cc = lane & 15;
#pragma unroll
    for (int mi = 0; mi < 8; ++mi) {
#pragma unroll
        for (int r = 0; r < 4; ++r) {
            int m = wr * 128 + mi * 16 + cr + r;
            if (m < rows) {
                if (MODE == 0) {
                    ushort_t* hp = (ushort_t*)Cout + (size_t)(goff + m) * NTOT
                                 + n0 + wc * 64 + cc;
#pragma unroll
                    for (int ni = 0; ni < 4; ++ni) {
                        float v = acc[mi][ni][r];
                        hp[ni * 16] = f2bf(v > 0.f ? v : 0.f);
                    }
                } else {
                    int tok = tokLds[m];
                    float p = probLds[m];
                    float* op = (float*)Cout + (size_t)tok * NTOT
                              + n0 + wc * 64 + cc;
#pragma unroll
                    for (int ni = 0; ni < 4; ++ni) op[ni * 16] = acc[mi][ni][r] * p;
                }
            }
        }
    }
#undef STAGE_A
#undef STAGE_B
#undef READ_A
#undef READ_B
#undef MFMA_P
}

// ---------------- workspace layout (unchanged) ----------------
constexpr size_t OFF_COUNTS  = 0;
constexpr size_t OFF_OFFSETS = 256;
constexpr size_t OFF_TILES   = 512;                                      // 5 arrays of 144 ints + nT
constexpr size_t OFF_TOPP    = OFF_TILES + 4 * 144 * 5 + 64;
constexpr size_t OFF_PERM    = OFF_TOPP + (size_t)T * 4;
constexpr size_t OFF_XG      = (OFF_PERM + (size_t)Eh * T * 4 + 255) & ~(size_t)255;
constexpr size_t OFF_H       = (OFF_XG + (size_t)(T + 128) * Dh * 2 + 255) & ~(size_t)255;
constexpr size_t OFF_WIN     = (OFF_H + (size_t)(T + 128) * Fh * 2 + 255) & ~(size_t)255;
constexpr size_t OFF_WOUT    = (OFF_WIN + (size_t)Eh * Dh * Fh * 2 + 255) & ~(size_t)255;

extern "C" void kernel_launch(void* const* d_in, const int* in_sizes, int n_in,
                              void* d_out, int out_size, void* d_ws, size_t ws_size,
                              hipStream_t stream) {
    const float* x    = (const float*)d_in[0];   // [T, Dh]
    const float* rw   = (const float*)d_in[1];   // [Dh, Eh]
    const float* w_in = (const float*)d_in[2];   // [Eh, Dh, Fh]
    const float* w_out= (const float*)d_in[3];   // [Eh, Fh, Dh]

    float* out    = (float*)d_out;               // [T, Dh]
    float* logits = out + (size_t)T * Dh;        // [T, Eh]
    float* eidx   = logits + (size_t)T * Eh;     // [T] (stored as float)

    char* ws = (char*)d_ws;
    int*      counts  = (int*)(ws + OFF_COUNTS);
    int*      offsets = (int*)(ws + OFF_OFFSETS);
    int*      tE      = (int*)(ws + OFF_TILES);
    int*      tGoff   = tE + 144;
    int*      tSlot0  = tGoff + 144;
    int*      tRows   = tSlot0 + 144;
    int*      nT      = tRows + 144;
    float*    topp    = (float*)(ws + OFF_TOPP);
    int*      perm    = (int*)(ws + OFF_PERM);
    ushort_t* Xg      = (ushort_t*)(ws + OFF_XG);
    ushort_t* h       = (ushort_t*)(ws + OFF_H);
    ushort_t* WinT    = (ushort_t*)(ws + OFF_WIN);   // [E][Fh][Dh]
    ushort_t* WoutT   = (ushort_t*)(ws + OFF_WOUT);  // [E][Dh][Fh]

    hipMemsetAsync(counts, 0, Eh * sizeof(int), stream);
    router_kernel<<<T / 16, 1024, 0, stream>>>(x, rw, logits, eidx, topp, counts, perm);
    scan_counts<<<1, 64, 0, stream>>>(counts, offsets, tE, tGoff, tSlot0, tRows, nT);
    gather_cast_x<<<(T * (Dh / 4)) / 256, 256, 0, stream>>>(x, offsets, perm, Xg);
    transpose_cvt<<<dim3(Fh / 32, Dh / 32, Eh), dim3(32, 8), 0, stream>>>(w_in, WinT, Dh, Fh);
    transpose_cvt<<<dim3(Dh / 32, Fh / 32, Eh), dim3(32, 8), 0, stream>>>(w_out, WoutT, Fh, Dh);
    moe_gemm2<Dh, Fh, 0><<<dim3(MAXT2, Fh / 256), 512, 0, stream>>>(
        Xg, WinT, tE, tGoff, tSlot0, tRows, nT, perm, topp, (void*)h);
    moe_gemm2<Fh, Dh, 1><<<dim3(MAXT2, Dh / 256), 512, 0, stream>>>(
        h, WoutT, tE, tGoff, tSlot0, tRows, nT, perm, topp, (void*)out);
}

// Round 3
// 499.799 us; speedup vs baseline: 1.0367x; 1.0367x over previous
//
#include <hip/hip_runtime.h>
#include <hip/hip_bf16.h>

// ---------------- problem constants ----------------
constexpr int T  = 16384;   // B*S tokens
constexpr int Dh = 768;
constexpr int Fh = 3072;
constexpr int Eh = 8;
constexpr int MAXT2 = T / 256 + Eh;   // 72 tiles max at 256-row granularity

typedef unsigned short ushort_t;
typedef __attribute__((ext_vector_type(8))) short  bf16x8;  // 8 bf16 = 4 VGPRs
typedef __attribute__((ext_vector_type(4))) float  f32x4;

// fp32 -> bf16 round-to-nearest-even (finite inputs)
static __device__ __forceinline__ ushort_t f2bf(float f) {
    unsigned u = __builtin_bit_cast(unsigned, f);
    u += 0x7FFFu + ((u >> 16) & 1u);
    return (ushort_t)(u >> 16);
}

// ---------------- router v2: 16 tokens per 1024-thread block ----------------
__global__ __launch_bounds__(1024) void router_kernel(
    const float* __restrict__ x, const float* __restrict__ rw,
    float* __restrict__ logits_out, float* __restrict__ eidx_out,
    float* __restrict__ topp, int* __restrict__ counts, int* __restrict__ perm) {

    __shared__ float rwT[Eh][Dh];   // 24 KB, transposed router weights
    __shared__ int   sAmax[16];
    __shared__ int   sBase[Eh];

    int tid = threadIdx.x;
    for (int i = tid; i < Dh * Eh; i += 1024) {
        int d = i >> 3, e = i & 7;
        rwT[e][d] = rw[i];
    }
    __syncthreads();

    int wave = tid >> 6, lane = tid & 63;
    int t = blockIdx.x * 16 + wave;
    const float* xr = x + (size_t)t * Dh;

    double acc[Eh];
#pragma unroll
    for (int e = 0; e < Eh; ++e) acc[e] = 0.0;

#pragma unroll
    for (int j = 0; j < Dh / 256; ++j) {
        int d = lane * 4 + j * 256;
        const float4 xv = *(const float4*)(xr + d);
#pragma unroll
        for (int e = 0; e < Eh; ++e) {
            const float4 w = *(const float4*)&rwT[e][d];
            acc[e] += (double)xv.x * (double)w.x + (double)xv.y * (double)w.y
                    + (double)xv.z * (double)w.z + (double)xv.w * (double)w.w;
        }
    }
#pragma unroll
    for (int off = 32; off > 0; off >>= 1) {
#pragma unroll
        for (int e = 0; e < Eh; ++e) acc[e] += __shfl_xor(acc[e], off, 64);
    }

    int amax = 0;
    if (lane == 0) {
        float l32[Eh];
        float m = -3.4e38f;
#pragma unroll
        for (int e = 0; e < Eh; ++e) l32[e] = (float)acc[e];
#pragma unroll
        for (int e = 0; e < Eh; ++e) {
            if (l32[e] > m) { m = l32[e]; amax = e; }  // strict > : first max wins
        }
        float s = 0.f;
#pragma unroll
        for (int e = 0; e < Eh; ++e) s += expf(l32[e] - m);
#pragma unroll
        for (int e = 0; e < Eh; ++e) logits_out[(size_t)t * Eh + e] = l32[e];
        eidx_out[t] = (float)amax;
        topp[t]     = 1.0f / s;
        sAmax[wave] = amax;
    }
    __syncthreads();

    if (tid < Eh) {
        int c = 0;
#pragma unroll
        for (int w = 0; w < 16; ++w) c += (sAmax[w] == tid);
        sBase[tid] = (c > 0) ? atomicAdd(&counts[tid], c) : 0;
    }
    __syncthreads();

    if (lane == 0) {
        int prior = 0;
        for (int w = 0; w < wave; ++w) prior += (sAmax[w] == amax);
        perm[amax * T + sBase[amax] + prior] = t;
    }
}

// ---------------- scan counts + build tile list: parallel over 8 lanes ----------------
__global__ void scan_counts(const int* counts, int* offsets,
                            int* tE, int* tGoff, int* tSlot0, int* tRows, int* nT) {
    int lane = threadIdx.x;
    if (lane < Eh) {
        int coff = 0, toff = 0;
        for (int e = 0; e < lane; ++e) {
            int ce = counts[e];
            coff += ce;
            toff += (ce + 255) >> 8;
        }
        int c = counts[lane];
        offsets[lane] = coff;
        int myt = (c + 255) >> 8;
        for (int k = 0; k < myt; ++k) {
            int idx = toff + k;
            tE[idx]     = lane;
            tGoff[idx]  = coff + k * 256;
            tSlot0[idx] = k * 256;
            int rem = c - k * 256;
            tRows[idx]  = rem < 256 ? rem : 256;
        }
        if (lane == Eh - 1) {
            offsets[Eh] = coff + c;
            nT[0] = toff + myt;
        }
    }
}

// ---------------- gather tokens into expert-sorted bf16 rows ----------------
__global__ void gather_cast_x(const float* __restrict__ x, const int* __restrict__ offsets,
                              const int* __restrict__ perm, ushort_t* __restrict__ Xg) {
    __shared__ int soff[Eh + 1];
    if (threadIdx.x < Eh + 1) soff[threadIdx.x] = offsets[threadIdx.x];
    __syncthreads();
    int q  = blockIdx.x * 256 + threadIdx.x;     // float4 index, exact grid
    int g  = q / (Dh / 4);
    int cq = (q - g * (Dh / 4)) * 4;
    int e = 0;
#pragma unroll
    for (int i = 1; i < Eh; ++i) e += (g >= soff[i]);
    int tok = perm[e * T + (g - soff[e])];
    const float4 v = *(const float4*)(x + (size_t)tok * Dh + cq);
    ushort4 o;
    o.x = f2bf(v.x); o.y = f2bf(v.y); o.z = f2bf(v.z); o.w = f2bf(v.w);
    *(ushort4*)(Xg + (size_t)g * Dh + cq) = o;
}

// ---------------- transpose + cast weights: src[R][C] fp32 -> dst[C][R] bf16 ----------------
__global__ void transpose_cvt(const float* __restrict__ src, ushort_t* __restrict__ dst,
                              int R, int C) {
    __shared__ ushort_t tile[32][33];
    int tx = threadIdx.x, ty = threadIdx.y;      // block (32, 8)
    size_t base = (size_t)blockIdx.z * (size_t)R * (size_t)C;
    int c0 = blockIdx.x * 32, r0 = blockIdx.y * 32;
#pragma unroll
    for (int j = 0; j < 4; ++j) {
        int r = ty + j * 8;
        tile[r][tx] = f2bf(src[base + (size_t)(r0 + r) * C + c0 + tx]);
    }
    __syncthreads();
    int idx = ty * 32 + tx;
#pragma unroll
    for (int j = 0; j < 2; ++j) {
        int lin = idx + j * 256;
        int c  = lin >> 4;
        int rp = (lin & 15) * 2;
        ushort2 o = { tile[rp][c], tile[rp + 1][c] };
        *(ushort2*)(dst + base + (size_t)(c0 + c) * R + r0 + rp) = o;
    }
}

// ---------------- grouped GEMM v5: 256x256 tile, 8 waves, overlap schedule ----------------
// A: [slot][KTOT] bf16 (expert-sorted rows). B: [E][NTOT][KTOT] bf16.
// LDS XOR-swizzle: row r's 16-B chunk g holds source chunk g ^ (r&7)
// (pre-swizzled global source, linear global_load_lds dest, swizzled ds_read).
// Wave (wr,wc): rows [wr*128,+128) x cols [wc*64,+64); acc[8][4] in AGPRs.
// Per K-tile (BK=64): ONLY 2 barriers.
//   entry: bb (8 B-frags) + afb[0] (mi=0 A-pair) preloaded during prior tile.
//   STAGE_A(t+1)->As[TB^1]; lgkmcnt(0) drain; barrier#1  (all waves' preloads done)
//   STAGE_B(t+2)->Bs[TB]   (region dead: B held in regs; safe after barrier#1)
//   8 phases mi=0..7: {read mi+1's 2 A-frags into alt buffer || 8 MFMA on cur}
//   phase 7: vmcnt(4) [A(t+1),B(t+1) landed; B(t+2) stays in flight] then preload
//            next tile's afb[0] / bb interleaved with the last 8 MFMA; barrier#2.
// Race-freedom: every LDS region is written only after (a) all waves drained reads
// of it (lgkm drain + barrier#1) or (b) the vmcnt chain proves prior data landed.
// MODE 0: h = relu(A*B^T) -> bf16, rows = global slot. MODE 1: out = prob*(A*B^T) -> fp32.
template<int KTOT, int NTOT, int MODE>
__global__ __launch_bounds__(512, 2) void moe_gemm2(
    const ushort_t* __restrict__ Aall, const ushort_t* __restrict__ Ball,
    const int* __restrict__ tE, const int* __restrict__ tGoff,
    const int* __restrict__ tSlot0, const int* __restrict__ tRows,
    const int* __restrict__ nT,
    const int* __restrict__ perm, const float* __restrict__ topp,
    void* __restrict__ Cout)
{
    int i = blockIdx.x;
    if (i >= nT[0]) return;
    int e     = tE[i];
    int goff  = tGoff[i];
    int slot0 = tSlot0[i];
    int rows  = tRows[i];
    int n0    = blockIdx.y * 256;

    const ushort_t* Ap = Aall + (size_t)goff * KTOT;
    const ushort_t* Bp = Ball + (size_t)e * KTOT * NTOT + (size_t)n0 * KTOT;

    __shared__ ushort_t As[2][256 * 64];   // 64 KB
    __shared__ ushort_t Bs[2][256 * 64];   // 64 KB
    __shared__ int   tokLds[256];
    __shared__ float probLds[256];

    int tid = threadIdx.x, lane = tid & 63, wid = tid >> 6;
    int wr = wid >> 2, wc = wid & 3;       // wave owns rows wr*128..+128, cols wc*64..+64
    int gq = lane >> 4, lm = lane & 15, l7 = lane & 7;

    if (MODE == 1 && tid < 256) {
        int tok = (tid < rows) ? perm[e * T + slot0 + tid] : 0;
        tokLds[tid]  = tok;
        probLds[tid] = (tid < rows) ? topp[tok] : 0.f;
    }

    f32x4 acc[8][4];                       // [mi 16-row frag][ni 16-col frag]
    const f32x4 zero = {0.f, 0.f, 0.f, 0.f};
#pragma unroll
    for (int mi = 0; mi < 8; ++mi)
#pragma unroll
        for (int ni = 0; ni < 4; ++ni) acc[mi][ni] = zero;

    bf16x8 bb0[4], bb1[4];                 // all 8 B-frags, resident across the K-tile
    bf16x8 afb[2][2];                      // ping-pong A-pair (indices const after unroll)

    // ---- staging: one full 256x64 tile = 4 x 16B loads/thread ----
#define STAGE_A(BUF, KT) { \
    _Pragma("unroll") \
    for (int j = 0; j < 4; ++j) { \
        int c_ = tid + j * 512; \
        int rr = c_ >> 3, gg = c_ & 7; \
        int srow_ = rr < rows ? rr : rows - 1; \
        const ushort_t* src_ = Ap + (size_t)srow_ * KTOT + (size_t)(KT) * 64 + ((gg ^ (rr & 7)) << 3); \
        __builtin_amdgcn_global_load_lds( \
            (const __attribute__((address_space(1))) unsigned int*)src_, \
            (__attribute__((address_space(3))) unsigned int*)&As[BUF][rr * 64 + gg * 8], 16, 0, 0); \
    } }

#define STAGE_B(BUF, KT) { \
    _Pragma("unroll") \
    for (int j = 0; j < 4; ++j) { \
        int c_ = tid + j * 512; \
        int rr = c_ >> 3, gg = c_ & 7; \
        const ushort_t* src_ = Bp + (size_t)rr * KTOT + (size_t)(KT) * 64 + ((gg ^ (rr & 7)) << 3); \
        __builtin_amdgcn_global_load_lds( \
            (const __attribute__((address_space(1))) unsigned int*)src_, \
            (__attribute__((address_space(3))) unsigned int*)&Bs[BUF][rr * 64 + gg * 8], 16, 0, 0); \
    } }

#define READ_B_KS(TB_, KS, DST) { \
    _Pragma("unroll") \
    for (int ni = 0; ni < 4; ++ni) \
        DST[ni] = *(const bf16x8*)&Bs[TB_][ \
            (wc * 64 + ni * 16 + lm) * 64 + (((((KS) << 2) + gq) ^ l7) << 3)]; \
    }

#define READ_A_MI(TB_, MI, DST) { \
    _Pragma("unroll") \
    for (int ks = 0; ks < 2; ++ks) \
        DST[ks] = *(const bf16x8*)&As[TB_][ \
            (wr * 128 + (MI) * 16 + lm) * 64 + ((((ks << 2) + gq) ^ l7) << 3)]; \
    }

#define MFMA_KS(MI, SRC, KS, BB) { \
    __builtin_amdgcn_s_setprio(1); \
    _Pragma("unroll") \
    for (int ni = 0; ni < 4; ++ni) \
        acc[MI][ni] = __builtin_amdgcn_mfma_f32_16x16x32_bf16( \
            SRC[KS], BB[ni], acc[MI][ni], 0, 0, 0); \
    __builtin_amdgcn_s_setprio(0); }

    const int nkt = KTOT / 64;

    // ---- prologue: tile 0 + B(1); vmcnt(4) guarantees tile 0; preload regs ----
    STAGE_A(0, 0);
    STAGE_B(0, 0);
    if (nkt > 1) {
        STAGE_B(1, 1);
        asm volatile("s_waitcnt vmcnt(4)" ::: "memory");
    } else {
        asm volatile("s_waitcnt vmcnt(0)" ::: "memory");
    }
    __builtin_amdgcn_sched_barrier(0);
    __builtin_amdgcn_s_barrier();
    READ_B_KS(0, 0, bb0);
    READ_B_KS(0, 1, bb1);
    READ_A_MI(0, 0, afb[0]);

    for (int t = 0; t < nkt; ++t) {
        const int TB = t & 1;

        if (t + 1 < nkt) STAGE_A(TB ^ 1, t + 1);
        asm volatile("s_waitcnt lgkmcnt(0)" ::: "memory");   // all preloads performed
        __builtin_amdgcn_sched_barrier(0);
        __builtin_amdgcn_s_barrier();                        // barrier #1
        if (t + 2 < nkt) STAGE_B(TB, t + 2);

#pragma unroll
        for (int mi = 0; mi < 7; ++mi) {
            READ_A_MI(TB, mi + 1, afb[(mi + 1) & 1]);        // read-ahead into alt buffer
            MFMA_KS(mi, afb[mi & 1], 0, bb0);
            MFMA_KS(mi, afb[mi & 1], 1, bb1);
        }

        // ---- mi = 7 (uses afb[1]); interleave next-tile preload ----
        if (t + 1 < nkt) {
            if (t + 2 < nkt) {
                asm volatile("s_waitcnt vmcnt(4)" ::: "memory");  // A(t+1),B(t+1) landed
            } else {
                asm volatile("s_waitcnt vmcnt(0)" ::: "memory");
            }
            __builtin_amdgcn_sched_barrier(0);
            READ_A_MI(TB ^ 1, 0, afb[0]);
            MFMA_KS(7, afb[1], 0, bb0);
            READ_B_KS(TB ^ 1, 0, bb0);
            MFMA_KS(7, afb[1], 1, bb1);
            READ_B_KS(TB ^ 1, 1, bb1);
        } else {
            MFMA_KS(7, afb[1], 0, bb0);
            MFMA_KS(7, afb[1], 1, bb1);
        }
        __builtin_amdgcn_s_barrier();                        // barrier #2 (tile boundary)
    }

    // ---- epilogue: C layout col = lane&15, row = (lane>>4)*4 + reg ----
    int cr = (lane >> 4) * 4;
    int cc = lane & 15;
#pragma unroll
    for (int mi = 0; mi < 8; ++mi) {
#pragma unroll
        for (int r = 0; r < 4; ++r) {
            int m = wr * 128 + mi * 16 + cr + r;
            if (m < rows) {
                if (MODE == 0) {
                    ushort_t* hp = (ushort_t*)Cout + (size_t)(goff + m) * NTOT
                                 + n0 + wc * 64 + cc;
#pragma unroll
                    for (int ni = 0; ni < 4; ++ni) {
                        float v = acc[mi][ni][r];
                        hp[ni * 16] = f2bf(v > 0.f ? v : 0.f);
                    }
                } else {
                    int tok = tokLds[m];
                    float p = probLds[m];
                    float* op = (float*)Cout + (size_t)tok * NTOT
                              + n0 + wc * 64 + cc;
#pragma unroll
                    for (int ni = 0; ni < 4; ++ni) op[ni * 16] = acc[mi][ni][r] * p;
                }
            }
        }
    }
#undef STAGE_A
#undef STAGE_B
#undef READ_B_KS
#undef READ_A_MI
#undef MFMA_KS
}

// ---------------- workspace layout (unchanged) ----------------
constexpr size_t OFF_COUNTS  = 0;
constexpr size_t OFF_OFFSETS = 256;
constexpr size_t OFF_TILES   = 512;                                      // 5 arrays of 144 ints + nT
constexpr size_t OFF_TOPP    = OFF_TILES + 4 * 144 * 5 + 64;
constexpr size_t OFF_PERM    = OFF_TOPP + (size_t)T * 4;
constexpr size_t OFF_XG      = (OFF_PERM + (size_t)Eh * T * 4 + 255) & ~(size_t)255;
constexpr size_t OFF_H       = (OFF_XG + (size_t)(T + 128) * Dh * 2 + 255) & ~(size_t)255;
constexpr size_t OFF_WIN     = (OFF_H + (size_t)(T + 128) * Fh * 2 + 255) & ~(size_t)255;
constexpr size_t OFF_WOUT    = (OFF_WIN + (size_t)Eh * Dh * Fh * 2 + 255) & ~(size_t)255;

extern "C" void kernel_launch(void* const* d_in, const int* in_sizes, int n_in,
                              void* d_out, int out_size, void* d_ws, size_t ws_size,
                              hipStream_t stream) {
    const float* x    = (const float*)d_in[0];   // [T, Dh]
    const float* rw   = (const float*)d_in[1];   // [Dh, Eh]
    const float* w_in = (const float*)d_in[2];   // [Eh, Dh, Fh]
    const float* w_out= (const float*)d_in[3];   // [Eh, Fh, Dh]

    float* out    = (float*)d_out;               // [T, Dh]
    float* logits = out + (size_t)T * Dh;        // [T, Eh]
    float* eidx   = logits + (size_t)T * Eh;     // [T] (stored as float)

    char* ws = (char*)d_ws;
    int*      counts  = (int*)(ws + OFF_COUNTS);
    int*      offsets = (int*)(ws + OFF_OFFSETS);
    int*      tE      = (int*)(ws + OFF_TILES);
    int*      tGoff   = tE + 144;
    int*      tSlot0  = tGoff + 144;
    int*      tRows   = tSlot0 + 144;
    int*      nT      = tRows + 144;
    float*    topp    = (float*)(ws + OFF_TOPP);
    int*      perm    = (int*)(ws + OFF_PERM);
    ushort_t* Xg      = (ushort_t*)(ws + OFF_XG);
    ushort_t* h       = (ushort_t*)(ws + OFF_H);
    ushort_t* WinT    = (ushort_t*)(ws + OFF_WIN);   // [E][Fh][Dh]
    ushort_t* WoutT   = (ushort_t*)(ws + OFF_WOUT);  // [E][Dh][Fh]

    hipMemsetAsync(counts, 0, Eh * sizeof(int), stream);
    router_kernel<<<T / 16, 1024, 0, stream>>>(x, rw, logits, eidx, topp, counts, perm);
    scan_counts<<<1, 64, 0, stream>>>(counts, offsets, tE, tGoff, tSlot0, tRows, nT);
    gather_cast_x<<<(T * (Dh / 4)) / 256, 256, 0, stream>>>(x, offsets, perm, Xg);
    transpose_cvt<<<dim3(Fh / 32, Dh / 32, Eh), dim3(32, 8), 0, stream>>>(w_in, WinT, Dh, Fh);
    transpose_cvt<<<dim3(Dh / 32, Fh / 32, Eh), dim3(32, 8), 0, stream>>>(w_out, WoutT, Fh, Dh);
    moe_gemm2<Dh, Fh, 0><<<dim3(MAXT2, Fh / 256), 512, 0, stream>>>(
        Xg, WinT, tE, tGoff, tSlot0, tRows, nT, perm, topp, (void*)h);
    moe_gemm2<Fh, Dh, 1><<<dim3(MAXT2, Dh / 256), 512, 0, stream>>>(
        h, WoutT, tE, tGoff, tSlot0, tRows, nT, perm, topp, (void*)out);
}